// Round 13
// baseline (239.171 us; speedup 1.0000x reference)
//
#include <hip/hip_runtime.h>

#define N_PTS 150000
#define NK 27
#define CIN 128
#define COUT 128
#define BM 128
#define NBLK ((N_PTS + BM - 1) / BM)   // 1172

typedef __attribute__((ext_vector_type(8))) short bfrag8;   // 8 bf16
typedef __attribute__((ext_vector_type(4))) float facc4;    // 4 f32

__device__ inline unsigned short f2bf(float f) {
    unsigned u = __builtin_bit_cast(unsigned, f);
    u += 0x7FFFu + ((u >> 16) & 1u);            // RNE
    return (unsigned short)(u >> 16);
}
__device__ inline unsigned pack2(float a, float b) {
    return (unsigned)f2bf(a) | ((unsigned)f2bf(b) << 16);
}
__device__ inline void glds16(const void* g, void* l) {
    __builtin_amdgcn_global_load_lds(
        (const __attribute__((address_space(1))) void*)g,
        (__attribute__((address_space(3))) void*)l, 16, 0, 0);
}

// ---- prep: fp32 data -> bf16, plus one zeroed row at index N_PTS ----
__global__ void cast_data_kernel(const float* __restrict__ in,
                                 unsigned short* __restrict__ out) {
    const int n8_data = N_PTS * (CIN / 8);
    const int n8_all  = (N_PTS + 1) * (CIN / 8);
    int i = blockIdx.x * blockDim.x + threadIdx.x;
    int stride = gridDim.x * blockDim.x;
    for (; i < n8_all; i += stride) {
        uint4 v;
        if (i < n8_data) {
            const float4* p = (const float4*)(in + (size_t)i * 8);
            float4 x = p[0], y = p[1];
            v.x = pack2(x.x, x.y); v.y = pack2(x.z, x.w);
            v.z = pack2(y.x, y.y); v.w = pack2(y.z, y.w);
        } else {
            v.x = v.y = v.z = v.w = 0u;
        }
        *(uint4*)(out + (size_t)i * 8) = v;
    }
}

// ---- prep: W[co][k][ci] -> frag-linear wkf[q][h][ct][kk][lane] (16B units) ----
// q = k*2+h2 (phase), h = wave cout-half, ct = cout quarter-tile, kk = K-step.
// unit: lane l holds W[co = h*64+ct*16+(l&15)][ci = (q&1)*64 + kk*32 + (l>>4)*8 ..+8]
__global__ void prep_weights_frag2(const float* __restrict__ w,
                                   unsigned short* __restrict__ wkf) {
    int i = blockIdx.x * blockDim.x + threadIdx.x;
    if (i >= 54 * 2 * 4 * 2 * 64) return;
    int l  = i & 63;
    int kk = (i >> 6) & 1;
    int ct = (i >> 7) & 3;
    int h  = (i >> 9) & 1;
    int q  = i >> 10;
    int k  = q >> 1, h2 = q & 1;
    int co = h * 64 + ct * 16 + (l & 15);
    int ci = h2 * 64 + kk * 32 + (l >> 4) * 8;
    const float4* src = (const float4*)(w + ((size_t)co * NK + k) * CIN + ci);
    float4 x = src[0], y = src[1];
    uint4 v;
    v.x = pack2(x.x, x.y); v.y = pack2(x.z, x.w);
    v.z = pack2(y.x, y.y); v.w = pack2(y.z, y.w);
    ((uint4*)wkf)[i] = v;
}

// ================= main kernel (v12: A triple-LDS, B direct-to-VGPR) =================
// 512 threads / 8 waves, BM=128, wave = 32 rows x 64 couts. 54 phases (K=64).
// A: glds gather via idx LDS slab (lgkm domain), TRIPLE buffer 3x16KB, 2 ahead.
// B: 8 frag loads global->VGPR per wave per phase (1KB coalesced wave-lines,
//    L1-served 4x intra-block reuse), double reg-set bx/by, issued 1 ahead.
// Queue invariant after each barrier: [A(p+2)x2, B(p+1)x8] -> WAIT_BAR(10).
// The only real wait is the compiler's pre-MFMA vmcnt (1 full phase of cover).
// LDS = 48K + 13.5K = 62,976 -> 2 blocks/CU.

#define STAGE_A(Q, ADST)                                                     \
  {                                                                          \
    const int k_  = (Q) >> 1;                                                \
    const int hb_ = ((Q) & 1) << 7;                                          \
    int iv0 = *(const int*)(ldsI + s0 * 108 + k_ * 4);                       \
    int iv1 = *(const int*)(ldsI + s1 * 108 + k_ * 4);                       \
    size_t e0 = (s0ok && iv0 >= 0) ? (size_t)iv0 : (size_t)N_PTS;            \
    size_t e1 = (s1ok && iv1 >= 0) ? (size_t)iv1 : (size_t)N_PTS;            \
    glds16(dbfB + e0 * 256 + hb_ + aswz, (ADST) + s0 * 128 + lu16);          \
    glds16(dbfB + e1 * 256 + hb_ + aswz, (ADST) + s1 * 128 + lu16);          \
  }

#define ISSUE_B(Q, BSET)                                                     \
  {                                                                          \
    const char* bs_ = wkfB + (size_t)(Q) * 16384 + h * 8192 + l * 16;        \
    _Pragma("unroll")                                                        \
    for (int j_ = 0; j_ < 8; ++j_)                                           \
      BSET[j_] = *(const uint4*)(bs_ + j_ * 1024);                           \
  }

#define MFMA_PHASE_R(ABUF, BSET)                                                    \
  {                                                                                 \
    __builtin_amdgcn_s_setprio(1);                                                  \
    _Pragma("unroll")                                                               \
    for (int kk = 0; kk < 2; ++kk) {                                                \
      const int sw_ = (((kk * 4 + lk) ^ (lr & 7)) << 4);                            \
      bfrag8 a0 = *(const bfrag8*)((ABUF) + (wrow * 32 + lr) * 128 + sw_);          \
      bfrag8 a1 = *(const bfrag8*)((ABUF) + (wrow * 32 + 16 + lr) * 128 + sw_);     \
      _Pragma("unroll")                                                             \
      for (int ct = 0; ct < 4; ++ct) {                                              \
        bfrag8 b = __builtin_bit_cast(bfrag8, BSET[ct * 2 + kk]);                   \
        acc[0][ct] = __builtin_amdgcn_mfma_f32_16x16x32_bf16(a0, b, acc[0][ct],     \
                                                             0, 0, 0);              \
        acc[1][ct] = __builtin_amdgcn_mfma_f32_16x16x32_bf16(a1, b, acc[1][ct],     \
                                                             0, 0, 0);              \
      }                                                                             \
    }                                                                               \
    __builtin_amdgcn_s_setprio(0);                                                  \
  }

#define WAIT_BAR(N)                                                          \
    __builtin_amdgcn_sched_barrier(0);                                       \
    asm volatile("s_waitcnt vmcnt(" #N ")" ::: "memory");                    \
    __builtin_amdgcn_s_barrier();                                            \
    __builtin_amdgcn_sched_barrier(0);

#define ROTATE_A                                                             \
    { char* tp = pA0; pA0 = pA1; pA1 = pA2; pA2 = tp; }

__global__ __launch_bounds__(512, 4)
void octconv_v12(const unsigned short* __restrict__ dbf,   // [N_PTS+1][128] bf16
                 const unsigned short* __restrict__ wkf,   // frag-linear weights
                 const int* __restrict__ nbr,
                 float* __restrict__ out) {
    // A triple 48K | idx 13.5K = 62976 B -> 2 blocks/CU
    __shared__ __align__(1024) unsigned char lds[3 * 16384 + 13824];

    const int t = threadIdx.x;
    const int w = t >> 6, l = t & 63;
    const int lr = l & 15, lk = l >> 4;
    const int h = w & 1, wrow = w >> 1;
    const int m0 = blockIdx.x * BM;

    // A staging: thread -> slots s0=(t>>3), s0+64; units l&7 (lane-linear dest)
    const int lu   = l & 7;
    const int lu16 = lu * 16;
    const int s0 = t >> 3;
    const int s1 = s0 + 64;
    const bool s0ok = (m0 + s0) < N_PTS;
    const bool s1ok = (m0 + s1) < N_PTS;
    const int aswz = (lu ^ (s0 & 7)) << 4;    // s1&7 == s0&7

    const char* dbfB = (const char*)dbf;
    const char* wkfB = (const char*)wkf;
    char* pA0 = (char*)lds;                    // A read (phase p)
    char* pA1 = (char*)lds + 16384;            // phase p+1
    char* pA2 = (char*)lds + 32768;            // phase p+2 (write target)
    char* ldsI = (char*)lds + 49152;

    facc4 acc[2][4];
    const facc4 fz = {0.f, 0.f, 0.f, 0.f};
#pragma unroll
    for (int a = 0; a < 2; ++a)
#pragma unroll
        for (int b = 0; b < 4; ++b) acc[a][b] = fz;

    uint4 bx[8], by[8];    // B frag double reg-set (static indices only)

    // ---- prologue 1: idx slab via glds (guarded at tail block) ----
    {
        const char* nsrc = (const char*)nbr + (size_t)m0 * 108;
        const int rows_valid = (N_PTS - m0) < BM ? (N_PTS - m0) : BM;
        const int nlimit = rows_valid * 108;
        int o;
        o = t * 16;        if (o < nlimit) glds16(nsrc + o, ldsI + o);
        o = 8192 + t * 16; if (t < 352 && o < nlimit) glds16(nsrc + o, ldsI + o);
    }
    WAIT_BAR(0)

    // ---- prologue 2: B(0)->bx, A(0), A(1); wait leaves A(1)x2 in flight ----
    ISSUE_B(0, bx)
    STAGE_A(0, pA0)
    STAGE_A(1, pA1)
    WAIT_BAR(2)

    // ---- kp = 0..25: uniform phase pairs ----
#pragma unroll 1
    for (int kp = 0; kp <= 25; ++kp) {
        const int p = 2 * kp;
        // even phase p: [in flight: A(p+1)x2]
        STAGE_A(p + 2, pA2)
        ISSUE_B(p + 1, by)
        MFMA_PHASE_R(pA0, bx)       // compiler pre-MFMA wait covers bx (1 phase old)
        WAIT_BAR(10)                // completes A(p+1); leaves A(p+2)x2 + by x8
        ROTATE_A
        // odd phase p+1
        STAGE_A(p + 3, pA2)
        ISSUE_B(p + 2, bx)
        MFMA_PHASE_R(pA0, by)
        WAIT_BAR(10)                // completes A(p+2); leaves A(p+3)x2 + bx x8
        ROTATE_A
    }

    // ---- kp = 26: phases 52, 53 ----
    ISSUE_B(53, by)
    MFMA_PHASE_R(pA0, bx)
    WAIT_BAR(8)                     // completes A(53); leaves by x8
    ROTATE_A
    MFMA_PHASE_R(pA0, by)           // compiler waits by

    // ---- epilogue: C/D col=lane&15, row=(lane>>4)*4+reg ----
#pragma unroll
    for (int rt = 0; rt < 2; ++rt) {
        const int r0 = m0 + wrow * 32 + rt * 16 + lk * 4;
#pragma unroll
        for (int ct = 0; ct < 4; ++ct) {
#pragma unroll
            for (int r = 0; r < 4; ++r) {
                int row = r0 + r;
                if (row < N_PTS)
                    out[(size_t)row * COUT + h * 64 + ct * 16 + lr] = acc[rt][ct][r];
            }
        }
    }
}

// ---- emergency fallback ----
__global__ void naive_kernel(const float* __restrict__ data, const float* __restrict__ wgt,
                             const int* __restrict__ nbr, float* __restrict__ out) {
    int mm = blockIdx.x;
    int co = threadIdx.x;
    if (mm >= N_PTS) return;
    float acc = 0.f;
    for (int k = 0; k < NK; ++k) {
        int idx = nbr[mm * NK + k];
        if (idx < 0) continue;
        const float* d  = data + (size_t)idx * CIN;
        const float* wp = wgt + ((size_t)co * NK + k) * CIN;
        for (int ci = 0; ci < CIN; ++ci) acc += d[ci] * wp[ci];
    }
    out[(size_t)mm * COUT + co] = acc;
}

extern "C" void kernel_launch(void* const* d_in, const int* in_sizes, int n_in,
                              void* d_out, int out_size, void* d_ws, size_t ws_size,
                              hipStream_t stream) {
    const float* data = (const float*)d_in[0];
    const float* wgt  = (const float*)d_in[1];
    const int*   nbr  = (const int*)d_in[2];
    float*       out  = (float*)d_out;

    const size_t wk_bytes  = (size_t)54 * 2 * 4 * 2 * 64 * 16;   // 884,736
    const size_t dbf_bytes = (size_t)(N_PTS + 1) * CIN * 2;      // 38,400,256

    if (ws_size < wk_bytes + dbf_bytes) {
        naive_kernel<<<N_PTS, COUT, 0, stream>>>(data, wgt, nbr, out);
        return;
    }
    unsigned short* wkf = (unsigned short*)d_ws;
    unsigned short* dbf = (unsigned short*)((char*)d_ws + wk_bytes);

    prep_weights_frag2<<<(54 * 2 * 4 * 2 * 64 + 255) / 256, 256, 0, stream>>>(wgt, wkf);
    cast_data_kernel<<<2048, 256, 0, stream>>>(data, dbf);

    octconv_v12<<<NBLK, 512, 0, stream>>>(dbf, wkf, nbr, out);
}

// Round 14
// 181.237 us; speedup vs baseline: 1.3197x; 1.3197x over previous
//
#include <hip/hip_runtime.h>

#define N_PTS 150000
#define NK 27
#define CIN 128
#define COUT 128
#define BM 128
#define NBLK ((N_PTS + BM - 1) / BM)   // 1172

typedef __attribute__((ext_vector_type(8))) short bfrag8;   // 8 bf16
typedef __attribute__((ext_vector_type(4))) float facc4;    // 4 f32

__device__ inline unsigned short f2bf(float f) {
    unsigned u = __builtin_bit_cast(unsigned, f);
    u += 0x7FFFu + ((u >> 16) & 1u);            // RNE
    return (unsigned short)(u >> 16);
}
__device__ inline unsigned pack2(float a, float b) {
    return (unsigned)f2bf(a) | ((unsigned)f2bf(b) << 16);
}
__device__ inline void glds16(const void* g, void* l) {
    __builtin_amdgcn_global_load_lds(
        (const __attribute__((address_space(1))) void*)g,
        (__attribute__((address_space(3))) void*)l, 16, 0, 0);
}

// ---- prep: fp32 data -> bf16, plus one zeroed row at index N_PTS ----
__global__ void cast_data_kernel(const float* __restrict__ in,
                                 unsigned short* __restrict__ out) {
    const int n8_data = N_PTS * (CIN / 8);
    const int n8_all  = (N_PTS + 1) * (CIN / 8);
    int i = blockIdx.x * blockDim.x + threadIdx.x;
    int stride = gridDim.x * blockDim.x;
    for (; i < n8_all; i += stride) {
        uint4 v;
        if (i < n8_data) {
            const float4* p = (const float4*)(in + (size_t)i * 8);
            float4 x = p[0], y = p[1];
            v.x = pack2(x.x, x.y); v.y = pack2(x.z, x.w);
            v.z = pack2(y.x, y.y); v.w = pack2(y.z, y.w);
        } else {
            v.x = v.y = v.z = v.w = 0u;
        }
        *(uint4*)(out + (size_t)i * 8) = v;
    }
}

// ---- prep: W[co][k][ci] -> wkh[k][h][co][bu] bf16 16B units, pre-swizzled bu^(co&7) ----
__global__ void prep_weights_h(const float* __restrict__ w,
                               unsigned short* __restrict__ wkh) {
    int i = blockIdx.x * blockDim.x + threadIdx.x;
    if (i >= NK * 2 * 128 * 8) return;
    int bu = i & 7, co = (i >> 3) & 127, h = (i >> 10) & 1, k = i >> 11;
    int ci = h * 64 + (bu ^ (co & 7)) * 8;
    const float4* src = (const float4*)(w + ((size_t)co * NK + k) * CIN + ci);
    float4 x = src[0], y = src[1];
    uint4 v;
    v.x = pack2(x.x, x.y); v.y = pack2(x.z, x.w);
    v.z = pack2(y.x, y.y); v.w = pack2(y.z, y.w);
    ((uint4*)wkh)[i] = v;
}

// ================= main kernel (v13 = v10 + triple-A + counted vmcnt(2)) =================
// 512 threads / 8 waves, BM=128, wave = 32 rows x 64 couts. 54 phases FULLY
// UNROLLED (compile-time phase ids -> static buffer names + static idx regs).
// A: glds gather, TRIPLE buffer 3x16KB, staged 2 phases ahead.
// B: glds, double buffer 2x16KB, staged 1 ahead. idx: VGPRs (iA/iB[27], loaded
// once in prologue; NEVER in the loop's vmcnt domain).
// Steady queue after each barrier: exactly [A(p+2) x2] -> WAIT_BAR(2).
// LDS = 3*16K + 2*16K = 81920 B exactly -> 2 blocks/CU (163840 = 160K).

#define STAGE_A(Q, ADST)                                                     \
  {                                                                          \
    const int hb_ = ((Q) & 1) << 7;                                          \
    int iv0 = iA[(Q) >> 1];                                                  \
    int iv1 = iB[(Q) >> 1];                                                  \
    size_t e0 = (s0ok && iv0 >= 0) ? (size_t)iv0 : (size_t)N_PTS;            \
    size_t e1 = (s1ok && iv1 >= 0) ? (size_t)iv1 : (size_t)N_PTS;            \
    glds16(dbfB + e0 * 256 + hb_ + aswz, (ADST) + s0 * 128 + lu16);          \
    glds16(dbfB + e1 * 256 + hb_ + aswz, (ADST) + s1 * 128 + lu16);          \
  }

#define STAGE_B(Q, BDST)                                                     \
  {                                                                          \
    const char* bs_ = wkhB + (size_t)(Q) * 16384 + t * 16;                   \
    glds16(bs_,        (BDST) + t * 16);                                     \
    glds16(bs_ + 8192, (BDST) + t * 16 + 8192);                              \
  }

#define MFMA_PHASE(ABUF, BBUF)                                                      \
  {                                                                                 \
    __builtin_amdgcn_s_setprio(1);                                                  \
    _Pragma("unroll")                                                               \
    for (int kk = 0; kk < 2; ++kk) {                                                \
      const int sw_ = (((kk * 4 + lk) ^ (lr & 7)) << 4);                            \
      bfrag8 a0 = *(const bfrag8*)((ABUF) + (wrow * 32 + lr) * 128 + sw_);          \
      bfrag8 a1 = *(const bfrag8*)((ABUF) + (wrow * 32 + 16 + lr) * 128 + sw_);     \
      _Pragma("unroll")                                                             \
      for (int ct = 0; ct < 4; ++ct) {                                              \
        bfrag8 b = *(const bfrag8*)((BBUF) + (h * 64 + ct * 16 + lr) * 128 + sw_);  \
        acc[0][ct] = __builtin_amdgcn_mfma_f32_16x16x32_bf16(a0, b, acc[0][ct],     \
                                                             0, 0, 0);              \
        acc[1][ct] = __builtin_amdgcn_mfma_f32_16x16x32_bf16(a1, b, acc[1][ct],     \
                                                             0, 0, 0);              \
      }                                                                             \
    }                                                                               \
    __builtin_amdgcn_s_setprio(0);                                                  \
  }

#define WAIT_BAR(N)                                                          \
    __builtin_amdgcn_sched_barrier(0);                                       \
    asm volatile("s_waitcnt vmcnt(" #N ")" ::: "memory");                    \
    __builtin_amdgcn_s_barrier();                                            \
    __builtin_amdgcn_sched_barrier(0);

// standard phase: {stage B(Q+1)->BW; stage A(Q+2)->AW; MFMA from AR,BR; wait 2}
#define PH_STD(Q, AR, AW, BR, BW)                                            \
    STAGE_B((Q) + 1, BW)                                                     \
    STAGE_A((Q) + 2, AW)                                                     \
    MFMA_PHASE(AR, BR)                                                       \
    WAIT_BAR(2)

// 6 phases = full buffer rotation period (A%3 x B%2), P must be %6==0
#define GROUP6(P)                                                            \
    PH_STD((P) + 0, pA0, pA2, pB0, pB1)                                      \
    PH_STD((P) + 1, pA1, pA0, pB1, pB0)                                      \
    PH_STD((P) + 2, pA2, pA1, pB0, pB1)                                      \
    PH_STD((P) + 3, pA0, pA2, pB1, pB0)                                      \
    PH_STD((P) + 4, pA1, pA0, pB0, pB1)                                      \
    PH_STD((P) + 5, pA2, pA1, pB1, pB0)

__global__ __launch_bounds__(512, 4)
void octconv_v13(const unsigned short* __restrict__ dbf,   // [N_PTS+1][128] bf16
                 const unsigned short* __restrict__ wkh,   // [27][2][128][8u] preswz
                 const int* __restrict__ nbr,
                 float* __restrict__ out) {
    // A triple 48K | B double 32K = 81920 B exactly -> 2 blocks/CU
    __shared__ __align__(1024) unsigned char lds[3 * 16384 + 2 * 16384];

    const int t = threadIdx.x;
    const int w = t >> 6, l = t & 63;
    const int lr = l & 15, lk = l >> 4;
    const int h = w & 1, wrow = w >> 1;
    const int m0 = blockIdx.x * BM;

    // A staging: thread -> slots s0=(t>>3), s0+64; units l&7 (lane-linear dest)
    const int lu   = l & 7;
    const int lu16 = lu * 16;
    const int s0 = t >> 3;
    const int s1 = s0 + 64;
    const bool s0ok = (m0 + s0) < N_PTS;
    const bool s1ok = (m0 + s1) < N_PTS;
    const int aswz = (lu ^ (s0 & 7)) << 4;    // s1&7 == s0&7

    const char* dbfB = (const char*)dbf;
    const char* wkhB = (const char*)wkh;
    char* pA0 = (char*)lds;                   // static buffer names (no rotation)
    char* pA1 = (char*)lds + 16384;
    char* pA2 = (char*)lds + 32768;
    char* pB0 = (char*)lds + 49152;
    char* pB1 = (char*)lds + 65536;

    facc4 acc[2][4];
    const facc4 fz = {0.f, 0.f, 0.f, 0.f};
#pragma unroll
    for (int a = 0; a < 2; ++a)
#pragma unroll
        for (int b = 0; b < 4; ++b) acc[a][b] = fz;

    // ---- prologue 1: idx -> VGPRs (one-time; outside loop vmcnt domain) ----
    int iA[27], iB[27];
    {
        const int r0 = (m0 + s0) < N_PTS ? (m0 + s0) : (N_PTS - 1);
        const int r1 = (m0 + s1) < N_PTS ? (m0 + s1) : (N_PTS - 1);
        const int* p0 = nbr + (size_t)r0 * NK;
        const int* p1 = nbr + (size_t)r1 * NK;
#pragma unroll
        for (int j = 0; j < 27; ++j) iA[j] = p0[j];
#pragma unroll
        for (int j = 0; j < 27; ++j) iB[j] = p1[j];
    }

    // ---- prologue 2: A(0),B(0),A(1) -> wait leaves A(1)x2 in flight ----
    STAGE_A(0, pA0)
    STAGE_B(0, pB0)
    STAGE_A(1, pA1)
    WAIT_BAR(2)

    // ---- phases 0..47: 8 full rotation groups ----
    GROUP6(0)  GROUP6(6)  GROUP6(12) GROUP6(18)
    GROUP6(24) GROUP6(30) GROUP6(36) GROUP6(42)

    // ---- phases 48..51 (uniform) ----
    PH_STD(48, pA0, pA2, pB0, pB1)
    PH_STD(49, pA1, pA0, pB1, pB0)
    PH_STD(50, pA2, pA1, pB0, pB1)
    PH_STD(51, pA0, pA2, pB1, pB0)   // stages A(53)->pA2, B(52)->pB0

    // ---- phase 52: stage B(53)->pB1; compute; drain all ----
    STAGE_B(53, pB1)
    MFMA_PHASE(pA1, pB0)
    WAIT_BAR(0)

    // ---- phase 53: compute only ----
    MFMA_PHASE(pA2, pB1)

    // ---- epilogue: C/D col=lane&15, row=(lane>>4)*4+reg ----
#pragma unroll
    for (int rt = 0; rt < 2; ++rt) {
        const int r0 = m0 + wrow * 32 + rt * 16 + lk * 4;
#pragma unroll
        for (int ct = 0; ct < 4; ++ct) {
#pragma unroll
            for (int r = 0; r < 4; ++r) {
                int row = r0 + r;
                if (row < N_PTS)
                    out[(size_t)row * COUT + h * 64 + ct * 16 + lr] = acc[rt][ct][r];
            }
        }
    }
}

// ---- emergency fallback ----
__global__ void naive_kernel(const float* __restrict__ data, const float* __restrict__ wgt,
                             const int* __restrict__ nbr, float* __restrict__ out) {
    int mm = blockIdx.x;
    int co = threadIdx.x;
    if (mm >= N_PTS) return;
    float acc = 0.f;
    for (int k = 0; k < NK; ++k) {
        int idx = nbr[mm * NK + k];
        if (idx < 0) continue;
        const float* d  = data + (size_t)idx * CIN;
        const float* wp = wgt + ((size_t)co * NK + k) * CIN;
        for (int ci = 0; ci < CIN; ++ci) acc += d[ci] * wp[ci];
    }
    out[(size_t)mm * COUT + co] = acc;
}

extern "C" void kernel_launch(void* const* d_in, const int* in_sizes, int n_in,
                              void* d_out, int out_size, void* d_ws, size_t ws_size,
                              hipStream_t stream) {
    const float* data = (const float*)d_in[0];
    const float* wgt  = (const float*)d_in[1];
    const int*   nbr  = (const int*)d_in[2];
    float*       out  = (float*)d_out;

    const size_t wk_bytes  = (size_t)NK * 2 * 128 * 8 * 16;    // 884,736
    const size_t dbf_bytes = (size_t)(N_PTS + 1) * CIN * 2;    // 38,400,256

    if (ws_size < wk_bytes + dbf_bytes) {
        naive_kernel<<<N_PTS, COUT, 0, stream>>>(data, wgt, nbr, out);
        return;
    }
    unsigned short* wkh = (unsigned short*)d_ws;
    unsigned short* dbf = (unsigned short*)((char*)d_ws + wk_bytes);

    prep_weights_h<<<(NK * 2 * 128 * 8 + 255) / 256, 256, 0, stream>>>(wgt, wkh);
    cast_data_kernel<<<2048, 256, 0, stream>>>(data, dbf);

    octconv_v13<<<NBLK, 512, 0, stream>>>(dbf, wkh, nbr, out);
}